// Round 4
// baseline (128.546 us; speedup 1.0000x reference)
//
#include <hip/hip_runtime.h>
#include <cstdint>
#include <cstddef>

#define NPTS 8192
#define NWORDS 128          // NPTS/64
#define XCOLS 10            // 3 coords + batch + feat + 5 seg
#define MIN_PTS 5
#define NGROUPS 10
#define BIGC 0x3fffffff

#define NLCAP 1536          // max nodes per group (expect ~820)
#define EACAP 8192          // per-group eps-pairs u<v (expect ~5.4k)
#define ELCAP 8192          // core-core edges
#define EBCAP 2048          // core-noncore edges
#define NT 1024             // 16 waves
#define NWV 16
#define ROUNDS 16

// One block per (batch,class) group. Everything lives in LDS; blocks are
// fully independent (no workspace, no atomics across blocks, no fences).
__global__ void __launch_bounds__(NT) k_all(const float* __restrict__ x,
                                            float* __restrict__ out) {
    __shared__ float4 pts[NLCAP];                    // 24 KB  (x,y,z, 0.5|p|^2-EPS2/4)
    __shared__ unsigned long long masks[NWORDS];     // 1 KB
    __shared__ int pref[NWORDS];                     // 0.5 KB
    __shared__ int nlist[NLCAP];                     // 6 KB
    __shared__ int sdeg[NLCAP];                      // 6 KB
    __shared__ int spar[NLCAP];                      // 6 KB
    __shared__ int scid[NLCAP];                      // 6 KB
    __shared__ int sbmin[NLCAP];                     // 6 KB
    __shared__ unsigned int eA[EACAP];               // 32 KB  all eps-pairs u<v
    __shared__ unsigned int eL[ELCAP];               // 32 KB  core-core
    __shared__ unsigned int eB[EBCAP];               // 8 KB   core-noncore
    __shared__ unsigned int corebm32[NLCAP / 32];    // 192 B
    __shared__ unsigned long long repbm[NLCAP / 64]; // 192 B
    __shared__ int pref24[NLCAP / 64];               // 96 B
    __shared__ int nnS, nA, nL, nB;
    __shared__ int sflagA[ROUNDS];
    // total ~128.1 KB (< 160 KB/CU)

    const int g = blockIdx.x;
    const int tid = threadIdx.x, lane = tid & 63, wv = tid >> 6;

    // ---- init
    for (int k = tid; k < NLCAP; k += NT) {
        pts[k] = make_float4(0.f, 0.f, 0.f, 1.0e38f);   // sentinel: never matches
        sdeg[k] = 0; spar[k] = k; sbmin[k] = BIGC;
    }
    if (tid == 0) { nA = 0; nL = 0; nB = 0; }
    if (tid < ROUNDS) sflagA[tid] = 0;

    // ---- membership: argmax(seg)+batch per point, ballot into 64-bit words
    for (int w = wv; w < NWORDS; w += NWV) {
        int i = w * 64 + lane;
        const float2* r2 = (const float2*)(x + (size_t)i * XCOLS);  // rows 40 B, 8-aligned
        float2 c23 = r2[1];                 // z, batch
        float2 c45 = r2[2];                 // feat, s0
        float2 c67 = r2[3];                 // s1, s2
        float2 c89 = r2[4];                 // s3, s4
        float best = c45.y; int bc = 0;
        if (c67.x > best) { best = c67.x; bc = 1; }
        if (c67.y > best) { best = c67.y; bc = 2; }
        if (c89.x > best) { best = c89.x; bc = 3; }
        if (c89.y > best) { best = c89.y; bc = 4; }
        unsigned long long bm = __ballot((int)c23.y * 5 + bc == g);
        if (lane == 0) masks[w] = bm;
    }
    __syncthreads();
    // ---- ordered positions: wave-0 scan of 128 popcounts (2 chunks of 64)
    if (wv == 0) {
        int v0 = __popcll(masks[lane]);
        int incl = v0;
        #pragma unroll
        for (int st = 1; st < 64; st <<= 1) {
            int o = __shfl_up(incl, st);
            if (lane >= st) incl += o;
        }
        pref[lane] = incl - v0;
        int tot0 = __shfl(incl, 63);
        int v1 = __popcll(masks[64 + lane]);
        int incl1 = v1;
        #pragma unroll
        for (int st = 1; st < 64; st <<= 1) {
            int o = __shfl_up(incl1, st);
            if (lane >= st) incl1 += o;
        }
        pref[64 + lane] = tot0 + incl1 - v1;
        if (lane == 63) nnS = tot0 + incl1;
    }
    __syncthreads();
    // ---- scatter member coords into pts + nlist
    for (int w = wv; w < NWORDS; w += NWV) {
        unsigned long long bm = masks[w];
        if ((bm >> lane) & 1ull) {
            int p = pref[w] + __popcll(bm & ((1ull << lane) - 1ull));
            if (p < NLCAP) {
                int i = w * 64 + lane;
                const float2* r2 = (const float2*)(x + (size_t)i * XCOLS);
                float2 c01 = r2[0]; float2 c23 = r2[1];
                float px = c01.x, py = c01.y, pz = c23.x;
                // d2<EPS2  <=>  dot(u,v) > wu+wv  with w = 0.5|p|^2 - EPS2/4
                pts[p] = make_float4(px, py, pz,
                                     0.5f * (px*px + py*py + pz*pz) - 56.25f);
                nlist[p] = i;
            }
        }
    }
    __syncthreads();
    const int NN = (nnS < NLCAP) ? nnS : NLCAP;
    const int NC = (NN + 31) >> 5;

    // ---- pairs: row-per-thread full sweep; edges (u<v) -> eA; full-row deg
    for (int rb = 0; rb < NLCAP; rb += NT) {
        if (rb + (wv << 6) >= NN) break;           // wave-uniform trim
        int r = rb + tid;                           // < NLCAP by construction
        float4 qu = pts[r];                         // sentinel rows yield no bits
        int rdeg = 0;
        for (int c = 0; c < NC; c++) {
            int base = c << 5;
            unsigned int bits = 0u;
            #pragma unroll
            for (int t = 0; t < 32; t++) {
                float4 qv = pts[base + t];          // wave-uniform broadcast
                float dt = qu.x*qv.x + qu.y*qv.y + qu.z*qv.z;
                bits |= (dt > qu.w + qv.w) ? (1u << t) : 0u;
            }
            rdeg += __popc(bits);                   // full row degree (incl self)
            int d = r - base;                       // keep only v > u for edges
            if (d >= 31) bits = 0u;
            else if (d >= 0) bits &= ~((2u << d) - 1u);
            int cnt = __popc(bits);
            int incl = cnt;
            #pragma unroll
            for (int st = 1; st < 64; st <<= 1) {
                int o = __shfl_up(incl, st);
                if (lane >= st) incl += o;
            }
            int tot = __shfl(incl, 63);
            if (tot > 0) {
                int rbse = 0;
                if (lane == 63) rbse = atomicAdd(&nA, tot);
                rbse = __shfl(rbse, 63);
                unsigned int p = (unsigned int)(rbse + incl - cnt);
                unsigned int b = bits;
                unsigned int uhi = (unsigned int)r << 11;
                while (b) {
                    int t = __ffs(b) - 1; b &= b - 1;
                    if (p < EACAP) eA[p] = uhi | (unsigned int)(base + t);
                    p++;
                }
            }
        }
        sdeg[r] = rdeg;                             // exclusive row owner
    }
    __syncthreads();
    const int NA = (nA > EACAP) ? EACAP : nA;

    // ---- core bitmap (32-bit words)
    for (int wd = tid; wd < NLCAP / 32; wd += NT) {
        unsigned int m = 0u;
        #pragma unroll
        for (int j = 0; j < 32; j++)
            m |= (sdeg[wd * 32 + j] >= MIN_PTS) ? (1u << j) : 0u;
        corebm32[wd] = m;
    }
    __syncthreads();
    auto corebit = [&](int l) -> bool { return (corebm32[l >> 5] >> (l & 31)) & 1u; };

    // ---- classify eA -> eL / eB (wave-aggregated compaction)
    for (int e0 = 0; e0 < NA; e0 += NT) {
        int e = e0 + tid;
        unsigned int pk = (e < NA) ? eA[e] : 0u;
        bool val = (e < NA);
        int u = (int)(pk >> 11), v = (int)(pk & 2047u);
        bool cu = val && corebit(u), cv = val && corebit(v);
        bool isL = cu && cv, isB = val && (cu != cv);
        unsigned long long mL = __ballot(isL);
        if (mL) {
            int b0 = 0;
            if (lane == 0) b0 = atomicAdd(&nL, __popcll(mL));
            b0 = __shfl(b0, 0);
            if (isL) {
                int idx = b0 + __popcll(mL & ((1ull << lane) - 1ull));
                if (idx < ELCAP) eL[idx] = pk;
            }
        }
        unsigned long long mB = __ballot(isB);
        if (mB) {
            int b0 = 0;
            if (lane == 0) b0 = atomicAdd(&nB, __popcll(mB));
            b0 = __shfl(b0, 0);
            if (isB) {
                int idx = b0 + __popcll(mB & ((1ull << lane) - 1ull));
                if (idx < EBCAP) eB[idx] = pk;
            }
        }
    }
    __syncthreads();
    const int NL = (nL > ELCAP) ? ELCAP : nL;
    const int NB = (nB > EBCAP) ? EBCAP : nB;

    // ---- SV: find-root hook + full path compression (values only decrease)
    for (int r = 0; r < ROUNDS; r++) {
        for (int k = tid; k < NL; k += NT) {
            unsigned int pk = eL[k];
            int u = (int)(pk >> 11), v = (int)(pk & 2047u);
            int ru = spar[u];
            while (true) { int p = spar[ru]; if (p == ru) break; ru = p; }
            int rv = spar[v];
            while (true) { int p = spar[rv]; if (p == rv) break; rv = p; }
            if (ru < rv)      { if (atomicMin(&spar[rv], ru) > ru) sflagA[r] = 1; }
            else if (rv < ru) { if (atomicMin(&spar[ru], rv) > rv) sflagA[r] = 1; }
        }
        __syncthreads();
        for (int k = tid; k < NN; k += NT) {
            int p = spar[k];
            while (true) { int q = spar[p]; if (q == p) break; p = q; }
            spar[k] = p;
        }
        __syncthreads();
        if (!sflagA[r]) break;
    }

    // ---- reps bitmap + parallel rank over 24 words
    for (int w = wv; w < NLCAP / 64; w += NWV) {
        int l = w * 64 + lane;
        bool isr = (l < NN) && corebit(l) && (spar[l] == l);
        unsigned long long bm = __ballot(isr);
        if (lane == 0) repbm[w] = bm;
    }
    __syncthreads();
    if (wv == 0 && lane < NLCAP / 64) {
        int c = __popcll(repbm[lane]);
        int incl = c;
        #pragma unroll
        for (int st = 1; st < 32; st <<= 1) {
            int o = __shfl_up(incl, st);
            if (lane >= st) incl += o;
        }
        pref24[lane] = incl - c;
    }
    __syncthreads();
    for (int w = wv; w < NLCAP / 64; w += NWV) {
        int l = w * 64 + lane;
        unsigned long long bm = repbm[w];
        if ((bm >> lane) & 1ull)
            scid[l] = pref24[w] + __popcll(bm & ((1ull << lane) - 1ull));
    }
    __syncthreads();
    // ---- core cluster id -> overwrite spar (read-all then write-all)
    int cc[2];
    #pragma unroll
    for (int t = 0; t < 2; t++) {
        int k = tid + t * NT;
        cc[t] = (k < NN && corebit(k)) ? scid[spar[k]] : BIGC;
    }
    __syncthreads();
    #pragma unroll
    for (int t = 0; t < 2; t++) {
        int k = tid + t * NT;
        if (k < NLCAP) spar[k] = (k < NN) ? cc[t] : BIGC;
    }
    __syncthreads();
    // ---- border: min adjacent core cid for the non-core endpoint
    for (int k = tid; k < NB; k += NT) {
        unsigned int pk = eB[k];
        int u = (int)(pk >> 11), v = (int)(pk & 2047u);
        int cu = spar[u], cv = spar[v];
        if (cu == BIGC) atomicMin(&sbmin[u], cv);
        else            atomicMin(&sbmin[v], cu);
    }
    __syncthreads();
    // ---- final labels + clustered output (blocks cover disjoint point sets)
    for (int k = tid; k < NN; k += NT) {
        int i = nlist[k];
        int c = spar[k];
        int lbl = (c != BIGC) ? c : ((sbmin[k] < BIGC) ? sbmin[k] : -1);
        out[i] = (float)lbl;
        const float* r = x + (size_t)i * XCOLS;
        float* o = out + NPTS + (size_t)i * 5;
        bool keep = lbl >= 0;
        #pragma unroll
        for (int c5 = 0; c5 < 5; c5++) o[c5] = keep ? r[c5] : 0.0f;
    }
}

extern "C" void kernel_launch(void* const* d_in, const int* in_sizes, int n_in,
                              void* d_out, int out_size, void* d_ws, size_t ws_size,
                              hipStream_t stream) {
    const float* x = (const float*)d_in[0];
    float* out = (float*)d_out;
    (void)d_ws; (void)ws_size;                      // no workspace needed
    k_all<<<NGROUPS, NT, 0, stream>>>(x, out);
}